// Round 7
// baseline (59.409 us; speedup 1.0000x reference)
//
#include <hip/hip_runtime.h>
#include <math.h>

#define NTH 256

static constexpr float HLP = 0.9189385332046727f; // 0.5*log(2*pi)

typedef __attribute__((ext_vector_type(2))) _Float16 half2v;
typedef __attribute__((ext_vector_type(2))) __fp16   fp16x2;

// ===================== main-path ws layout (float/dword indices) =====================
// [0, 61440)       f16-pair packed weights, layers 0..3. region rbase*256 dwords;
//                  dword (i*8+k)*4 + jp = half2(w[i*8+2jp][k], w[i*8+2jp+1][k])
//                  rbase: L0 r -> r | L1 -> 128+r | L2 -> 192+r | L3 -> 224+r
// [WTTd, +3840)    f16-pair packed transposed weights layers 4..7:
//                  dword reg*256 + k*32 + ((i^k)&7)*4 + jp
//                  reg: L4 r=0..7 -> 0..7 | L5 -> 8..11 | L6 -> 12..13 | L7 -> 14
// [AOF2, +2048)    leafA = exp(-log_sigma)   [256][8]  f32
// [BOF2, +2048)    leafB = -log_sigma - HLP  [256][8]  f32
// [ROF2, +8)       srw = softmax(root_w) f32
// [L1NF, +2097152) L1 n f16-packed uint4 [64][8192]
// [L1MF, +524288)  L1 M f32 [64][8192]
// [L3NF, +524288)  L3 n f16-packed uint4 [16][8192]
// [L3MF, +131072)  L3 M f32 [16][8192]
static constexpr int WTTd = 61440;
static constexpr int AOF2 = 65280;
static constexpr int BOF2 = 67328;
static constexpr int ROF2 = 69376;
static constexpr int L1NF = 69632;
static constexpr int L1MF = L1NF + 2097152;   // 2166784
static constexpr int L3NF = L1MF + 524288;    // 2691072
static constexpr int L3MF = L3NF + 524288;    // 3215360
static constexpr size_t WS_NEED_B = (size_t)(L3MF + 131072) * 4;  // 13,385,728

// ===================== helpers =====================
__device__ __forceinline__ half2v pkrtz(float a, float b) {
  return __builtin_bit_cast(half2v, __builtin_amdgcn_cvt_pkrtz(a, b));
}
__device__ __forceinline__ half2v u2h(unsigned u) {
  return __builtin_bit_cast(half2v, u);
}
__device__ __forceinline__ unsigned h2u(half2v h) {
  return __builtin_bit_cast(unsigned, h);
}
// dot2 accumulate: a.lo*b.lo + a.hi*b.hi + c
__device__ __forceinline__ float dd(half2v a, half2v b, float c) {
#if __has_builtin(__builtin_amdgcn_fdot2)
  return __builtin_amdgcn_fdot2(__builtin_bit_cast(fp16x2, a),
                                __builtin_bit_cast(fp16x2, b), c, false);
#else
  return fmaf((float)a[0], (float)b[0], fmaf((float)a[1], (float)b[1], c));
#endif
}
__device__ __forceinline__ float max8(const float* s) {
  float m = s[0];
  #pragma unroll
  for (int k = 1; k < 8; ++k) m = fmaxf(m, s[k]);
  return m;
}

// leaf eval producing duplicated-pair (A-side) form
__device__ __forceinline__ void leaf_ii(float xv, const float* mu8, const float* A8,
                                        const float* B8, half2v* ii, float* M) {
  float h[8];
  float m = -3.0e38f;
  #pragma unroll
  for (int k = 0; k < 8; ++k) {
    const float z = (xv - mu8[k]) * A8[k];
    h[k] = fmaf(-0.5f * z, z, B8[k]);
    m = fmaxf(m, h[k]);
  }
  #pragma unroll
  for (int k = 0; k < 8; ++k) {
    const float n = __expf(h[k] - m);
    ii[k] = pkrtz(n, n);
  }
  *M = m;
}
// leaf eval producing packed-pair (B-side) form
__device__ __forceinline__ void leaf_pk(float xv, const float* mu8, const float* A8,
                                        const float* B8, half2v* pk, float* M) {
  float h[8];
  float m = -3.0e38f;
  #pragma unroll
  for (int k = 0; k < 8; ++k) {
    const float z = (xv - mu8[k]) * A8[k];
    h[k] = fmaf(-0.5f * z, z, B8[k]);
    m = fmaxf(m, h[k]);
  }
  #pragma unroll
  for (int p = 0; p < 4; ++p) {
    const float n0 = __expf(h[2 * p] - m);
    const float n1 = __expf(h[2 * p + 1] - m);
    pk[p] = pkrtz(n0, n1);
  }
  *M = m;
}

// combine via dot2: s[k] = sum_{i,j} na_i nb_j W[i*8+j][k]
template<int G, bool OUT_II>
__device__ __forceinline__ void combine_d2(const uint4* __restrict__ WL,
                                           const half2v (&na)[G][8],
                                           const half2v (&nb)[G][4],
                                           half2v (&oii)[G][8],
                                           half2v (&opk)[G][4],
                                           float (&M)[G]) {
  float s[G][8];
  #pragma unroll
  for (int g = 0; g < G; ++g)
    #pragma unroll
    for (int k = 0; k < 8; ++k) s[g][k] = 0.f;

  #pragma unroll
  for (int i = 0; i < 8; ++i) {
    half2v e[G][4];
    #pragma unroll
    for (int g = 0; g < G; ++g) {
      e[g][0] = na[g][i] * nb[g][0];
      e[g][1] = na[g][i] * nb[g][1];
      e[g][2] = na[g][i] * nb[g][2];
      e[g][3] = na[g][i] * nb[g][3];
    }
    #pragma unroll
    for (int k = 0; k < 8; ++k) {
      const uint4 w = WL[i * 8 + k];
      #pragma unroll
      for (int g = 0; g < G; ++g) {
        float acc = s[g][k];
        acc = dd(e[g][0], u2h(w.x), acc);
        acc = dd(e[g][1], u2h(w.y), acc);
        acc = dd(e[g][2], u2h(w.z), acc);
        acc = dd(e[g][3], u2h(w.w), acc);
        s[g][k] = acc;
      }
    }
  }
  #pragma unroll
  for (int g = 0; g < G; ++g) {
    const float smax = max8(s[g]);
    const float inv = 1.0f / smax;
    if constexpr (OUT_II) {
      #pragma unroll
      for (int p = 0; p < 8; ++p) {
        const float n = s[g][p] * inv;
        oii[g][p] = pkrtz(n, n);
      }
    } else {
      #pragma unroll
      for (int p = 0; p < 4; ++p)
        opk[g][p] = pkrtz(s[g][2 * p] * inv, s[g][2 * p + 1] * inv);
    }
    M[g] += __logf(smax);
  }
}

// ===================== prep5: region-parallel softmax -> f16-pair weights =====================
// grid: 256 blocks. blocks 0..239: L0-3 region rbase=blockIdx. 240..254: L4-7 reg.
// block 255: leaf consts + root softmax.
__global__ __launch_bounds__(256) void spn_prep5(
    const float* __restrict__ ls,
    const float* __restrict__ w0, const float* __restrict__ w1,
    const float* __restrict__ w2, const float* __restrict__ w3,
    const float* __restrict__ w4, const float* __restrict__ w5,
    const float* __restrict__ w6, const float* __restrict__ w7,
    const float* __restrict__ root_w,
    float* __restrict__ ws)
{
  const int blk = blockIdx.x;
  const int tid = threadIdx.x;
  unsigned* wdw = reinterpret_cast<unsigned*>(ws);

  if (blk == 255) {
    // leaf constants (2048 entries, 8 per thread) + root softmax
    #pragma unroll
    for (int i = 0; i < 8; ++i) {
      const int idx = tid + i * 256;
      const float l = ls[idx];
      ws[AOF2 + idx] = __expf(-l);
      ws[BOF2 + idx] = -l - HLP;
    }
    if (tid == 0) {
      float m = -3.0e38f;
      for (int k = 0; k < 8; ++k) m = fmaxf(m, root_w[k]);
      float e[8]; float t = 0.f;
      for (int k = 0; k < 8; ++k) { e[k] = __expf(root_w[k] - m); t += e[k]; }
      const float inv = 1.0f / t;
      for (int k = 0; k < 8; ++k) ws[ROF2 + k] = e[k] * inv;
    }
    return;
  }

  __shared__ float lsw[512];
  const float* src;
  bool transposed = false;
  int reg = 0;
  if (blk < 128)       src = w0 + blk * 512;
  else if (blk < 192)  src = w1 + (blk - 128) * 512;
  else if (blk < 224)  src = w2 + (blk - 192) * 512;
  else if (blk < 240)  src = w3 + (blk - 224) * 512;
  else {
    transposed = true;
    reg = blk - 240;
    if (reg < 8)       src = w4 + reg * 512;
    else if (reg < 12) src = w5 + (reg - 8) * 512;
    else if (reg < 14) src = w6 + (reg - 12) * 512;
    else               src = w7;
  }
  lsw[tid]       = src[tid];
  lsw[tid + 256] = src[tid + 256];
  __syncthreads();

  if (tid < 8) {
    const int k = tid;
    float v[64];
    float m = -3.0e38f;
    #pragma unroll
    for (int c = 0; c < 64; ++c) { v[c] = lsw[c * 8 + k]; m = fmaxf(m, v[c]); }
    float t = 0.f;
    #pragma unroll
    for (int c = 0; c < 64; ++c) { v[c] = __expf(v[c] - m); t += v[c]; }
    const float inv = 1.0f / t;
    if (!transposed) {
      #pragma unroll
      for (int i = 0; i < 8; ++i)
        #pragma unroll
        for (int jp = 0; jp < 4; ++jp)
          wdw[blk * 256 + (i * 8 + k) * 4 + jp] =
              h2u(pkrtz(v[i * 8 + 2 * jp] * inv, v[i * 8 + 2 * jp + 1] * inv));
    } else {
      #pragma unroll
      for (int i = 0; i < 8; ++i)
        #pragma unroll
        for (int jp = 0; jp < 4; ++jp)
          wdw[WTTd + reg * 256 + k * 32 + (((i ^ k) & 7) << 2) + jp] =
              h2u(pkrtz(v[i * 8 + 2 * jp] * inv, v[i * 8 + 2 * jp + 1] * inv));
    }
  }
}

// ===================== L01: leaves + L0 x2 + L1, G=4, dot2 =====================
// grid: 64 r1 x 8 chunks = 512 blocks x 256 thr; thread = 4 batches
__global__ __launch_bounds__(NTH, 3) void spn_L01e(
    const float* __restrict__ x,
    const float* __restrict__ mu,
    float* __restrict__ ws)
{
  __shared__ uint4 wsh4[192];   // 3 regions x 64 uint4
  __shared__ float lsh[96];     // mu, leafA, leafB for 4 features x 8
  const int tid = threadIdx.x;
  const int r1 = blockIdx.x >> 3;
  const int chunk = blockIdx.x & 7;
  const uint4* wg = reinterpret_cast<const uint4*>(ws);

  if (tid < 192) {
    const int reg = tid >> 6;
    const int rbase = (reg < 2) ? (2 * r1 + reg) : (128 + r1);
    wsh4[tid] = wg[rbase * 64 + (tid & 63)];
  }
  if (tid < 96) {
    const int f8 = r1 * 32;
    lsh[tid] = (tid < 32) ? mu[f8 + tid]
             : (tid < 64) ? ws[AOF2 + f8 + (tid - 32)]
                          : ws[BOF2 + f8 + (tid - 64)];
  }
  __syncthreads();

  const int b0 = chunk * 1024 + tid;    // batches b0 + 256*g
  float4 xv[4];
  #pragma unroll
  for (int g = 0; g < 4; ++g)
    xv[g] = *reinterpret_cast<const float4*>(x + (size_t)(b0 + 256 * g) * 256 + 4 * r1);

  half2v ii[4][8], pk[4][4];
  half2v cAii[4][8], cBpk[4][4];
  half2v dmy_ii[4][8], dmy_pk[4][4];
  float MA[4], MB[4];
  float Ma, Mb;

  // pair A: features 4r1+0 (A-side), 4r1+1 (B-side)
  #pragma unroll
  for (int g = 0; g < 4; ++g) {
    leaf_ii(xv[g].x, lsh + 0, lsh + 32, lsh + 64, ii[g], &Ma);
    leaf_pk(xv[g].y, lsh + 8, lsh + 40, lsh + 72, pk[g], &Mb);
    MA[g] = Ma + Mb;
  }
  combine_d2<4, true>(wsh4, ii, pk, cAii, dmy_pk, MA);

  // pair B: features 4r1+2, 4r1+3
  #pragma unroll
  for (int g = 0; g < 4; ++g) {
    leaf_ii(xv[g].z, lsh + 16, lsh + 48, lsh + 80, ii[g], &Ma);
    leaf_pk(xv[g].w, lsh + 24, lsh + 56, lsh + 88, pk[g], &Mb);
    MB[g] = Ma + Mb;
  }
  combine_d2<4, false>(wsh4 + 64, ii, pk, dmy_ii, cBpk, MB);

  float M[4];
  #pragma unroll
  for (int g = 0; g < 4; ++g) M[g] = MA[g] + MB[g];
  half2v n[4][4];
  combine_d2<4, false>(wsh4 + 128, cAii, cBpk, dmy_ii, n, M);

  uint4* outn = reinterpret_cast<uint4*>(ws + L1NF);
  #pragma unroll
  for (int g = 0; g < 4; ++g) {
    outn[r1 * 8192 + b0 + 256 * g] =
        uint4{h2u(n[g][0]), h2u(n[g][1]), h2u(n[g][2]), h2u(n[g][3])};
    ws[L1MF + r1 * 8192 + b0 + 256 * g] = M[g];
  }
}

// packed uint4 -> duplicated-pair form
__device__ __forceinline__ void mk_ii(uint4 p, half2v* ii) {
  const half2v a0 = u2h(p.x), a1 = u2h(p.y), a2 = u2h(p.z), a3 = u2h(p.w);
  ii[0] = __builtin_shufflevector(a0, a0, 0, 0);
  ii[1] = __builtin_shufflevector(a0, a0, 1, 1);
  ii[2] = __builtin_shufflevector(a1, a1, 0, 0);
  ii[3] = __builtin_shufflevector(a1, a1, 1, 1);
  ii[4] = __builtin_shufflevector(a2, a2, 0, 0);
  ii[5] = __builtin_shufflevector(a2, a2, 1, 1);
  ii[6] = __builtin_shufflevector(a3, a3, 0, 0);
  ii[7] = __builtin_shufflevector(a3, a3, 1, 1);
}

// ===================== L23: L2 x2 + L3, G=2, dot2 =====================
// grid: 16 r3 x 16 chunks = 256 blocks x 256 thr; thread = 2 batches
__global__ __launch_bounds__(NTH, 4) void spn_L23e(float* __restrict__ ws)
{
  __shared__ uint4 wsh4[192];
  const int tid = threadIdx.x;
  const int r3 = blockIdx.x >> 4;
  const int chunk = blockIdx.x & 15;
  const uint4* wg = reinterpret_cast<const uint4*>(ws);

  if (tid < 192) {
    const int reg = tid >> 6;
    const int rbase = (reg < 2) ? (192 + 2 * r3 + reg) : (224 + r3);
    wsh4[tid] = wg[rbase * 64 + (tid & 63)];
  }
  __syncthreads();

  const int b0 = chunk * 512 + tid;   // batches b0, b0+256
  const uint4* n4 = reinterpret_cast<const uint4*>(ws + L1NF);

  half2v ii[2][8], pk[2][4];
  half2v cAii[2][8], cBpk[2][4];
  half2v dmy_ii[2][8], dmy_pk[2][4];
  float MA[2], MB[2];

  #pragma unroll
  for (int g = 0; g < 2; ++g) {
    const int b = b0 + 256 * g;
    const uint4 p0 = n4[(4 * r3 + 0) * 8192 + b];
    const uint4 p1 = n4[(4 * r3 + 1) * 8192 + b];
    mk_ii(p0, ii[g]);
    pk[g][0] = u2h(p1.x); pk[g][1] = u2h(p1.y); pk[g][2] = u2h(p1.z); pk[g][3] = u2h(p1.w);
    MA[g] = ws[L1MF + (4 * r3 + 0) * 8192 + b] + ws[L1MF + (4 * r3 + 1) * 8192 + b];
  }
  combine_d2<2, true>(wsh4, ii, pk, cAii, dmy_pk, MA);

  #pragma unroll
  for (int g = 0; g < 2; ++g) {
    const int b = b0 + 256 * g;
    const uint4 p2 = n4[(4 * r3 + 2) * 8192 + b];
    const uint4 p3 = n4[(4 * r3 + 3) * 8192 + b];
    mk_ii(p2, ii[g]);
    pk[g][0] = u2h(p3.x); pk[g][1] = u2h(p3.y); pk[g][2] = u2h(p3.z); pk[g][3] = u2h(p3.w);
    MB[g] = ws[L1MF + (4 * r3 + 2) * 8192 + b] + ws[L1MF + (4 * r3 + 3) * 8192 + b];
  }
  combine_d2<2, false>(wsh4 + 64, ii, pk, dmy_ii, cBpk, MB);

  float M[2] = {MA[0] + MB[0], MA[1] + MB[1]};
  half2v n[2][4];
  combine_d2<2, false>(wsh4 + 128, cAii, cBpk, dmy_ii, n, M);

  #pragma unroll
  for (int g = 0; g < 2; ++g) {
    reinterpret_cast<uint4*>(ws + L3NF)[r3 * 8192 + b0 + 256 * g] =
        uint4{h2u(n[g][0]), h2u(n[g][1]), h2u(n[g][2]), h2u(n[g][3])};
    ws[L3MF + r3 * 8192 + b0 + 256 * g] = M[g];
  }
}

// ===================== tail: layers 4..7 + root, k-parallel, dot2 =====================
__device__ __forceinline__ float macTd(const uint4* __restrict__ Wr, int myk,
                                       const float* na, const half2v* nbpk) {
  float s = 0.f;
  #pragma unroll
  for (int i = 0; i < 8; ++i) {
    const uint4 w = Wr[myk * 8 + ((i ^ myk) & 7)];
    float T = dd(nbpk[0], u2h(w.x), 0.f);
    T = dd(nbpk[1], u2h(w.y), T);
    T = dd(nbpk[2], u2h(w.z), T);
    T = dd(nbpk[3], u2h(w.w), T);
    s = fmaf(na[i], T, s);
  }
  return s;
}

__global__ __launch_bounds__(NTH) void spn_taild(float* __restrict__ ws,
                                                 float* __restrict__ out)
{
  __shared__ uint4 wsh4[960];   // 15 regions x 64 uint4 = 15 KB
  __shared__ float ssh[8];
  const int tid = threadIdx.x;
  const uint4* wg = reinterpret_cast<const uint4*>(ws);
  #pragma unroll
  for (int i = 0; i < 4; ++i) {
    const int idx = tid + i * 256;
    if (idx < 960) wsh4[idx] = wg[WTTd / 4 + idx];
  }
  if (tid < 8) ssh[tid] = ws[ROF2 + tid];
  __syncthreads();

  const int lane = tid & 63, wid = tid >> 6;
  const int myk = lane & 7, bsub = lane >> 3, gbase = lane & 56;
  const int b = blockIdx.x * 32 + wid * 8 + bsub;

  const uint4* n4 = reinterpret_cast<const uint4*>(ws + L3NF);

  // ---- layer 4: 8 regions
  float n4v[8], M4[8];
  #pragma unroll
  for (int r = 0; r < 8; ++r) {
    const uint4 pa = n4[(2 * r + 0) * 8192 + b];
    const uint4 pb = n4[(2 * r + 1) * 8192 + b];
    const float Ma = ws[L3MF + (2 * r + 0) * 8192 + b];
    const float Mb = ws[L3MF + (2 * r + 1) * 8192 + b];
    float na[8];
    const half2v a0 = u2h(pa.x), a1 = u2h(pa.y), a2 = u2h(pa.z), a3 = u2h(pa.w);
    na[0] = (float)a0[0]; na[1] = (float)a0[1];
    na[2] = (float)a1[0]; na[3] = (float)a1[1];
    na[4] = (float)a2[0]; na[5] = (float)a2[1];
    na[6] = (float)a3[0]; na[7] = (float)a3[1];
    half2v nbpk[4] = {u2h(pb.x), u2h(pb.y), u2h(pb.z), u2h(pb.w)};
    float s = macTd(wsh4 + r * 64, myk, na, nbpk);
    float m = s;
    m = fmaxf(m, __shfl_xor(m, 1)); m = fmaxf(m, __shfl_xor(m, 2)); m = fmaxf(m, __shfl_xor(m, 4));
    n4v[r] = s / m;
    M4[r] = Ma + Mb + __logf(m);
  }

  // ---- layer 5: 4 regions
  float n5v[4], M5[4];
  #pragma unroll
  for (int r = 0; r < 4; ++r) {
    float na[8]; half2v nbpk[4];
    #pragma unroll
    for (int i = 0; i < 8; ++i) na[i] = __shfl(n4v[2 * r], gbase + i, 64);
    #pragma unroll
    for (int p = 0; p < 4; ++p)
      nbpk[p] = pkrtz(__shfl(n4v[2 * r + 1], gbase + 2 * p, 64),
                      __shfl(n4v[2 * r + 1], gbase + 2 * p + 1, 64));
    float s = macTd(wsh4 + (8 + r) * 64, myk, na, nbpk);
    float m = s;
    m = fmaxf(m, __shfl_xor(m, 1)); m = fmaxf(m, __shfl_xor(m, 2)); m = fmaxf(m, __shfl_xor(m, 4));
    n5v[r] = s / m;
    M5[r] = M4[2 * r] + M4[2 * r + 1] + __logf(m);
  }

  // ---- layer 6: 2 regions
  float n6v[2], M6[2];
  #pragma unroll
  for (int r = 0; r < 2; ++r) {
    float na[8]; half2v nbpk[4];
    #pragma unroll
    for (int i = 0; i < 8; ++i) na[i] = __shfl(n5v[2 * r], gbase + i, 64);
    #pragma unroll
    for (int p = 0; p < 4; ++p)
      nbpk[p] = pkrtz(__shfl(n5v[2 * r + 1], gbase + 2 * p, 64),
                      __shfl(n5v[2 * r + 1], gbase + 2 * p + 1, 64));
    float s = macTd(wsh4 + (12 + r) * 64, myk, na, nbpk);
    float m = s;
    m = fmaxf(m, __shfl_xor(m, 1)); m = fmaxf(m, __shfl_xor(m, 2)); m = fmaxf(m, __shfl_xor(m, 4));
    n6v[r] = s / m;
    M6[r] = M5[2 * r] + M5[2 * r + 1] + __logf(m);
  }

  // ---- layer 7 + root
  {
    float na[8]; half2v nbpk[4];
    #pragma unroll
    for (int i = 0; i < 8; ++i) na[i] = __shfl(n6v[0], gbase + i, 64);
    #pragma unroll
    for (int p = 0; p < 4; ++p)
      nbpk[p] = pkrtz(__shfl(n6v[1], gbase + 2 * p, 64),
                      __shfl(n6v[1], gbase + 2 * p + 1, 64));
    float s = macTd(wsh4 + 14 * 64, myk, na, nbpk);
    float m = s;
    m = fmaxf(m, __shfl_xor(m, 1)); m = fmaxf(m, __shfl_xor(m, 2)); m = fmaxf(m, __shfl_xor(m, 4));
    const float n7 = s / m;
    const float M7 = M6[0] + M6[1] + __logf(m);
    float prod = n7 * ssh[myk];
    prod += __shfl_xor(prod, 1); prod += __shfl_xor(prod, 2); prod += __shfl_xor(prod, 4);
    if (myk == 0) out[b] = M7 + __logf(prod);
  }
}

// ===================== fallback path (R1 kernel, proven 145us) =====================
static constexpr int NW   = 130560;
static constexpr int AOFF = NW;
static constexpr int BOFF = NW + 2048;
static constexpr int ROFF = NW + 4096;

__device__ __forceinline__ void leaf_eval(float xv, const float* mu8, const float* A8,
                                          const float* B8, float* n, float* M) {
  float h[8];
  float m = -3.0e38f;
  #pragma unroll
  for (int k = 0; k < 8; ++k) {
    const float z = (xv - mu8[k]) * A8[k];
    h[k] = fmaf(-0.5f * z, z, B8[k]);
    m = fmaxf(m, h[k]);
  }
  #pragma unroll
  for (int k = 0; k < 8; ++k) n[k] = __expf(h[k] - m);
  *M = m;
}

__global__ __launch_bounds__(256) void spn_prep(
    const float* __restrict__ ls,
    const float* __restrict__ w0, const float* __restrict__ w1,
    const float* __restrict__ w2, const float* __restrict__ w3,
    const float* __restrict__ w4, const float* __restrict__ w5,
    const float* __restrict__ w6, const float* __restrict__ w7,
    const float* __restrict__ root_w,
    float* __restrict__ ws)
{
  const int job = blockIdx.x * blockDim.x + threadIdx.x;
  if (job < 2040) {
    const float* wl[8] = {w0, w1, w2, w3, w4, w5, w6, w7};
    int j = job, l = 0, base = 0, R = 128;
    while (j >= R * 8) { j -= R * 8; base += R * 512; R >>= 1; ++l; }
    const int r = j >> 3, k = j & 7;
    const float* src = wl[l] + r * 512 + k;
    float v[64];
    float m = -3.0e38f;
    #pragma unroll
    for (int c = 0; c < 64; ++c) { v[c] = src[c * 8]; m = fmaxf(m, v[c]); }
    float ssum = 0.f;
    #pragma unroll
    for (int c = 0; c < 64; ++c) { v[c] = __expf(v[c] - m); ssum += v[c]; }
    const float inv = 1.0f / ssum;
    float* dst = ws + base + r * 512 + k;
    #pragma unroll
    for (int c = 0; c < 64; ++c) dst[c * 8] = v[c] * inv;
  } else if (job < 2040 + 2048) {
    const int i = job - 2040;
    const float l = ls[i];
    ws[AOFF + i] = __expf(-l);
    ws[BOFF + i] = -l - HLP;
  } else if (job == 2040 + 2048) {
    float m = -3.0e38f;
    for (int k = 0; k < 8; ++k) m = fmaxf(m, root_w[k]);
    float e[8]; float ssum = 0.f;
    for (int k = 0; k < 8; ++k) { e[k] = __expf(root_w[k] - m); ssum += e[k]; }
    const float inv = 1.0f / ssum;
    for (int k = 0; k < 8; ++k) ws[ROFF + k] = e[k] * inv;
  }
}

__device__ __forceinline__ void mac64(const float* __restrict__ Wr,
                                      const float* na, const float* nb,
                                      float* s) {
  #pragma unroll
  for (int k = 0; k < 8; ++k) s[k] = 0.f;
  #pragma unroll
  for (int i = 0; i < 8; ++i) {
    const float ai = na[i];
    #pragma unroll
    for (int j = 0; j < 8; ++j) {
      const float e = ai * nb[j];
      const float4 wA = *reinterpret_cast<const float4*>(Wr + (i * 8 + j) * 8);
      const float4 wB = *reinterpret_cast<const float4*>(Wr + (i * 8 + j) * 8 + 4);
      s[0] = fmaf(e, wA.x, s[0]); s[1] = fmaf(e, wA.y, s[1]);
      s[2] = fmaf(e, wA.z, s[2]); s[3] = fmaf(e, wA.w, s[3]);
      s[4] = fmaf(e, wB.x, s[4]); s[5] = fmaf(e, wB.y, s[5]);
      s[6] = fmaf(e, wB.z, s[6]); s[7] = fmaf(e, wB.w, s[7]);
    }
  }
}

#define TB 8
static constexpr int PLA = 128 * 9 + 5;
static constexpr int PLB = 64 * 9 + 5;
static constexpr int NAO = 0;
static constexpr int NBO = TB * PLA;
static constexpr int MAO = NBO + TB * PLB;
static constexpr int MBO = MAO + TB * 128;
static constexpr int SMEM_F = MBO + TB * 64;

__global__ __launch_bounds__(NTH, 2) void spn_main_fb(
    const float* __restrict__ x,
    const float* __restrict__ mu,
    const float* __restrict__ ws,
    float* __restrict__ out)
{
  const float* leafA = ws + AOFF;
  const float* leafB = ws + BOFF;
  const float* srw   = ws + ROFF;

  __shared__ float smem[SMEM_F];

  const int tid = threadIdx.x;
  const int bB = blockIdx.x * TB;

  {
    const float* W0 = ws;
    for (int it = tid; it < TB * 128; it += NTH) {
      const int bb = it & (TB - 1), r = it >> 3;
      float na[8], nb[8], Ma, Mb;
      const int f0 = 2 * r;
      const float xv0 = x[(bB + bb) * 256 + f0];
      const float xv1 = x[(bB + bb) * 256 + f0 + 1];
      leaf_eval(xv0, mu + f0 * 8, leafA + f0 * 8, leafB + f0 * 8, na, &Ma);
      leaf_eval(xv1, mu + f0 * 8 + 8, leafA + f0 * 8 + 8, leafB + f0 * 8 + 8, nb, &Mb);
      float s[8];
      mac64(W0 + r * 512, na, nb, s);
      const float smax = max8(s);
      const float inv = 1.0f / smax;
      const int ob = NAO + bb * PLA + r * 9;
      #pragma unroll
      for (int k = 0; k < 8; ++k) smem[ob + k] = s[k] * inv;
      smem[MAO + bb * 128 + r] = Ma + Mb + __logf(smax);
    }
  }
  __syncthreads();

  int pinO = NAO, poutO = NBO;
  int MinO = MAO, MoutO = MBO;
  int PLIN = PLA, PLOUT = PLB;
  int Rin = 128;
  const float* Wl = ws + 128 * 512;
  for (int l = 1; l < 7; ++l) {
    const int Rout = Rin >> 1;
    for (int it = tid; it < TB * Rout; it += NTH) {
      const int bb = it & (TB - 1), r = it >> 3;
      float na[8], nb[8];
      const int ia = pinO + bb * PLIN + (2 * r) * 9;
      #pragma unroll
      for (int i = 0; i < 8; ++i) { na[i] = smem[ia + i]; nb[i] = smem[ia + 9 + i]; }
      float s[8];
      mac64(Wl + r * 512, na, nb, s);
      const float smax = max8(s);
      const float inv = 1.0f / smax;
      const int ob = poutO + bb * PLOUT + r * 9;
      #pragma unroll
      for (int k = 0; k < 8; ++k) smem[ob + k] = s[k] * inv;
      smem[MoutO + bb * Rout + r] =
          smem[MinO + bb * Rin + 2 * r] + smem[MinO + bb * Rin + 2 * r + 1] + __logf(smax);
    }
    __syncthreads();
    int t;
    t = pinO; pinO = poutO; poutO = t;
    t = MinO; MinO = MoutO; MoutO = t;
    t = PLIN; PLIN = PLOUT; PLOUT = t;
    Rin = Rout;
    Wl += Rout * 512;
  }

  for (int it = tid; it < TB; it += NTH) {
    const int bb = it;
    float na[8], nb[8];
    const int ia = pinO + bb * PLIN;
    #pragma unroll
    for (int i = 0; i < 8; ++i) { na[i] = smem[ia + i]; nb[i] = smem[ia + 9 + i]; }
    float s[8];
    mac64(Wl, na, nb, s);
    float acc = 0.f;
    #pragma unroll
    for (int k = 0; k < 8; ++k) acc = fmaf(s[k], srw[k], acc);
    out[bB + bb] = smem[MinO + bb * 2] + smem[MinO + bb * 2 + 1] + __logf(acc);
  }
}

extern "C" void kernel_launch(void* const* d_in, const int* in_sizes, int n_in,
                              void* d_out, int out_size, void* d_ws, size_t ws_size,
                              hipStream_t stream) {
  (void)in_sizes; (void)n_in; (void)out_size;
  const float* x      = (const float*)d_in[0];
  const float* mu     = (const float*)d_in[1];
  const float* ls     = (const float*)d_in[2];
  const float* w0     = (const float*)d_in[3];
  const float* w1     = (const float*)d_in[4];
  const float* w2     = (const float*)d_in[5];
  const float* w3     = (const float*)d_in[6];
  const float* w4     = (const float*)d_in[7];
  const float* w5     = (const float*)d_in[8];
  const float* w6     = (const float*)d_in[9];
  const float* w7     = (const float*)d_in[10];
  const float* root_w = (const float*)d_in[11];
  float* ws  = (float*)d_ws;
  float* out = (float*)d_out;

  if (ws_size >= WS_NEED_B) {
    spn_prep5<<<256, 256, 0, stream>>>(ls, w0, w1, w2, w3, w4, w5, w6, w7, root_w, ws);
    spn_L01e<<<512, NTH, 0, stream>>>(x, mu, ws);
    spn_L23e<<<256, NTH, 0, stream>>>(ws);
    spn_taild<<<256, NTH, 0, stream>>>(ws, out);
  } else {
    spn_prep<<<16, 256, 0, stream>>>(ls, w0, w1, w2, w3, w4, w5, w6, w7, root_w, ws);
    spn_main_fb<<<8192 / TB, NTH, 0, stream>>>(x, mu, ws, out);
  }
}

// Round 8
// 51.748 us; speedup vs baseline: 1.1481x; 1.1481x over previous
//
#include <hip/hip_runtime.h>
#include <math.h>

#define NTH 256

static constexpr float HLP = 0.9189385332046727f; // 0.5*log(2*pi)

typedef __attribute__((ext_vector_type(2))) _Float16 half2v;
typedef __attribute__((ext_vector_type(2))) __fp16   fp16x2;

// ===================== main-path ws layout (float indices) =====================
// [0, 2097152)        L1 n f16-packed uint4 [64][8192]   (uint4 idx r1*8192+b)
// [2097152, 2621440)  L1 M f32 [64][8192]
// [2621440, 3145728)  L3 n f16-packed uint4 [16][8192]
// [3145728, 3276800)  L3 M f32 [16][8192]
static constexpr int L1MF = 2097152;
static constexpr int L3NF = 2621440;
static constexpr int L3MF = 3145728;
static constexpr size_t WS_NEED_B = (size_t)3276800 * 4;   // 13,107,200 (< proven 13.39MB)

// ===================== helpers =====================
__device__ __forceinline__ half2v pkrtz(float a, float b) {
  return __builtin_bit_cast(half2v, __builtin_amdgcn_cvt_pkrtz(a, b));
}
__device__ __forceinline__ half2v u2h(unsigned u) {
  return __builtin_bit_cast(half2v, u);
}
__device__ __forceinline__ unsigned h2u(half2v h) {
  return __builtin_bit_cast(unsigned, h);
}
__device__ __forceinline__ float dd(half2v a, half2v b, float c) {
#if __has_builtin(__builtin_amdgcn_fdot2)
  return __builtin_amdgcn_fdot2(__builtin_bit_cast(fp16x2, a),
                                __builtin_bit_cast(fp16x2, b), c, false);
#else
  return fmaf((float)a[0], (float)b[0], fmaf((float)a[1], (float)b[1], c));
#endif
}
__device__ __forceinline__ float max8(const float* s) {
  float m = s[0];
  #pragma unroll
  for (int k = 1; k < 8; ++k) m = fmaxf(m, s[k]);
  return m;
}

__device__ __forceinline__ void leaf_ii(float xv, const float* mu8, const float* A8,
                                        const float* B8, half2v* ii, float* M) {
  float h[8];
  float m = -3.0e38f;
  #pragma unroll
  for (int k = 0; k < 8; ++k) {
    const float z = (xv - mu8[k]) * A8[k];
    h[k] = fmaf(-0.5f * z, z, B8[k]);
    m = fmaxf(m, h[k]);
  }
  #pragma unroll
  for (int k = 0; k < 8; ++k) {
    const float n = __expf(h[k] - m);
    ii[k] = pkrtz(n, n);
  }
  *M = m;
}
__device__ __forceinline__ void leaf_pk(float xv, const float* mu8, const float* A8,
                                        const float* B8, half2v* pk, float* M) {
  float h[8];
  float m = -3.0e38f;
  #pragma unroll
  for (int k = 0; k < 8; ++k) {
    const float z = (xv - mu8[k]) * A8[k];
    h[k] = fmaf(-0.5f * z, z, B8[k]);
    m = fmaxf(m, h[k]);
  }
  #pragma unroll
  for (int p = 0; p < 4; ++p) {
    const float n0 = __expf(h[2 * p] - m);
    const float n1 = __expf(h[2 * p + 1] - m);
    pk[p] = pkrtz(n0, n1);
  }
  *M = m;
}

// combine via dot2: s[k] = sum_{i,j} na_i nb_j W[i*8+j][k]
template<int G, bool OUT_II>
__device__ __forceinline__ void combine_d2(const uint4* __restrict__ WL,
                                           const half2v (&na)[G][8],
                                           const half2v (&nb)[G][4],
                                           half2v (&oii)[G][8],
                                           half2v (&opk)[G][4],
                                           float (&M)[G]) {
  float s[G][8];
  #pragma unroll
  for (int g = 0; g < G; ++g)
    #pragma unroll
    for (int k = 0; k < 8; ++k) s[g][k] = 0.f;

  #pragma unroll
  for (int i = 0; i < 8; ++i) {
    half2v e[G][4];
    #pragma unroll
    for (int g = 0; g < G; ++g) {
      e[g][0] = na[g][i] * nb[g][0];
      e[g][1] = na[g][i] * nb[g][1];
      e[g][2] = na[g][i] * nb[g][2];
      e[g][3] = na[g][i] * nb[g][3];
    }
    #pragma unroll
    for (int k = 0; k < 8; ++k) {
      const uint4 w = WL[i * 8 + k];
      #pragma unroll
      for (int g = 0; g < G; ++g) {
        float acc = s[g][k];
        acc = dd(e[g][0], u2h(w.x), acc);
        acc = dd(e[g][1], u2h(w.y), acc);
        acc = dd(e[g][2], u2h(w.z), acc);
        acc = dd(e[g][3], u2h(w.w), acc);
        s[g][k] = acc;
      }
    }
  }
  #pragma unroll
  for (int g = 0; g < G; ++g) {
    const float smax = max8(s[g]);
    const float inv = 1.0f / smax;
    if constexpr (OUT_II) {
      #pragma unroll
      for (int p = 0; p < 8; ++p) {
        const float n = s[g][p] * inv;
        oii[g][p] = pkrtz(n, n);
      }
    } else {
      #pragma unroll
      for (int p = 0; p < 4; ++p)
        opk[g][p] = pkrtz(s[g][2 * p] * inv, s[g][2 * p + 1] * inv);
    }
    M[g] += __logf(smax);
  }
}

// block-local softmax of one column (r,k) from stage into packed [c][k]-pair layout
__device__ __forceinline__ void prep_col_std(const float* stage, unsigned* wdwL,
                                             int r, int k) {
  float v[64];
  float m = -3.0e38f;
  #pragma unroll
  for (int c = 0; c < 64; ++c) { v[c] = stage[r * 512 + c * 8 + k]; m = fmaxf(m, v[c]); }
  float t = 0.f;
  #pragma unroll
  for (int c = 0; c < 64; ++c) { v[c] = __expf(v[c] - m); t += v[c]; }
  const float inv = 1.0f / t;
  #pragma unroll
  for (int i = 0; i < 8; ++i)
    #pragma unroll
    for (int jp = 0; jp < 4; ++jp)
      wdwL[r * 256 + (i * 8 + k) * 4 + jp] =
          h2u(pkrtz(v[i * 8 + 2 * jp] * inv, v[i * 8 + 2 * jp + 1] * inv));
}

// ===================== K1: self-prep + leaves + L0 x2 + L1, G=2 =====================
// grid: 64 r1 x 16 chunks = 1024 blocks x 256 thr; thread = 2 batches
__global__ __launch_bounds__(NTH, 4) void spn_a(
    const float* __restrict__ x,
    const float* __restrict__ mu,
    const float* __restrict__ ls,
    const float* __restrict__ w0,
    const float* __restrict__ w1,
    float* __restrict__ ws)
{
  __shared__ float stage[1536];
  __shared__ uint4 wsh4[192];   // 3 regions x 64 uint4
  __shared__ float lsh[96];     // mu, leafA, leafB for 4 features x 8
  const int tid = threadIdx.x;
  const int r1 = blockIdx.x >> 4;
  const int chunk = blockIdx.x & 15;

  // stage raw weights for this block's 3 regions (coalesced)
  #pragma unroll
  for (int i = 0; i < 6; ++i) {
    const int idx = tid + 256 * i;
    const int reg = idx >> 9, off = idx & 511;
    const float* src = (reg == 0) ? (w0 + (2 * r1) * 512)
                     : (reg == 1) ? (w0 + (2 * r1 + 1) * 512)
                                  : (w1 + r1 * 512);
    stage[idx] = src[off];
  }
  if (tid < 96) {
    const int f8 = r1 * 32;
    if (tid < 32)      lsh[tid] = mu[f8 + tid];
    else if (tid < 64) lsh[tid] = __expf(-ls[f8 + (tid - 32)]);
    else               lsh[tid] = -ls[f8 + (tid - 64)] - HLP;
  }
  __syncthreads();

  if (tid < 24) prep_col_std(stage, reinterpret_cast<unsigned*>(wsh4), tid >> 3, tid & 7);
  __syncthreads();

  const int b0 = chunk * 512 + tid;    // batches b0, b0+256
  const float4 xv0 = *reinterpret_cast<const float4*>(x + (size_t)b0 * 256 + 4 * r1);
  const float4 xv1 = *reinterpret_cast<const float4*>(x + (size_t)(b0 + 256) * 256 + 4 * r1);

  half2v ii[2][8], pk[2][4];
  half2v cAii[2][8], cBpk[2][4];
  half2v dmy_ii[2][8], dmy_pk[2][4];
  float MA[2], MB[2];
  float Ma, Mb;

  leaf_ii(xv0.x, lsh + 0, lsh + 32, lsh + 64, ii[0], &Ma);
  leaf_pk(xv0.y, lsh + 8, lsh + 40, lsh + 72, pk[0], &Mb);
  MA[0] = Ma + Mb;
  leaf_ii(xv1.x, lsh + 0, lsh + 32, lsh + 64, ii[1], &Ma);
  leaf_pk(xv1.y, lsh + 8, lsh + 40, lsh + 72, pk[1], &Mb);
  MA[1] = Ma + Mb;
  combine_d2<2, true>(wsh4, ii, pk, cAii, dmy_pk, MA);

  leaf_ii(xv0.z, lsh + 16, lsh + 48, lsh + 80, ii[0], &Ma);
  leaf_pk(xv0.w, lsh + 24, lsh + 56, lsh + 88, pk[0], &Mb);
  MB[0] = Ma + Mb;
  leaf_ii(xv1.z, lsh + 16, lsh + 48, lsh + 80, ii[1], &Ma);
  leaf_pk(xv1.w, lsh + 24, lsh + 56, lsh + 88, pk[1], &Mb);
  MB[1] = Ma + Mb;
  combine_d2<2, false>(wsh4 + 64, ii, pk, dmy_ii, cBpk, MB);

  float M[2] = {MA[0] + MB[0], MA[1] + MB[1]};
  half2v n[2][4];
  combine_d2<2, false>(wsh4 + 128, cAii, cBpk, dmy_ii, n, M);

  uint4* outn = reinterpret_cast<uint4*>(ws);
  outn[r1 * 8192 + b0]       = uint4{h2u(n[0][0]), h2u(n[0][1]), h2u(n[0][2]), h2u(n[0][3])};
  outn[r1 * 8192 + b0 + 256] = uint4{h2u(n[1][0]), h2u(n[1][1]), h2u(n[1][2]), h2u(n[1][3])};
  ws[L1MF + r1 * 8192 + b0]       = M[0];
  ws[L1MF + r1 * 8192 + b0 + 256] = M[1];
}

// packed uint4 -> duplicated-pair form
__device__ __forceinline__ void mk_ii(uint4 p, half2v* ii) {
  const half2v a0 = u2h(p.x), a1 = u2h(p.y), a2 = u2h(p.z), a3 = u2h(p.w);
  ii[0] = __builtin_shufflevector(a0, a0, 0, 0);
  ii[1] = __builtin_shufflevector(a0, a0, 1, 1);
  ii[2] = __builtin_shufflevector(a1, a1, 0, 0);
  ii[3] = __builtin_shufflevector(a1, a1, 1, 1);
  ii[4] = __builtin_shufflevector(a2, a2, 0, 0);
  ii[5] = __builtin_shufflevector(a2, a2, 1, 1);
  ii[6] = __builtin_shufflevector(a3, a3, 0, 0);
  ii[7] = __builtin_shufflevector(a3, a3, 1, 1);
}

// ===================== K2: self-prep + L2 x2 + L3, G=1 =====================
// grid: 16 r3 x 32 chunks = 512 blocks x 256 thr
__global__ __launch_bounds__(NTH, 4) void spn_b(
    const float* __restrict__ w2,
    const float* __restrict__ w3,
    float* __restrict__ ws)
{
  __shared__ float stage[1536];
  __shared__ uint4 wsh4[192];
  const int tid = threadIdx.x;
  const int r3 = blockIdx.x >> 5;
  const int chunk = blockIdx.x & 31;

  #pragma unroll
  for (int i = 0; i < 6; ++i) {
    const int idx = tid + 256 * i;
    const int reg = idx >> 9, off = idx & 511;
    const float* src = (reg == 0) ? (w2 + (2 * r3) * 512)
                     : (reg == 1) ? (w2 + (2 * r3 + 1) * 512)
                                  : (w3 + r3 * 512);
    stage[idx] = src[off];
  }
  __syncthreads();
  if (tid < 24) prep_col_std(stage, reinterpret_cast<unsigned*>(wsh4), tid >> 3, tid & 7);
  __syncthreads();

  const int b = chunk * 256 + tid;
  const uint4* n4 = reinterpret_cast<const uint4*>(ws);
  const uint4 p0 = n4[(4 * r3 + 0) * 8192 + b];
  const uint4 p1 = n4[(4 * r3 + 1) * 8192 + b];
  const uint4 p2 = n4[(4 * r3 + 2) * 8192 + b];
  const uint4 p3 = n4[(4 * r3 + 3) * 8192 + b];
  const float M0 = ws[L1MF + (4 * r3 + 0) * 8192 + b];
  const float M1 = ws[L1MF + (4 * r3 + 1) * 8192 + b];
  const float M2 = ws[L1MF + (4 * r3 + 2) * 8192 + b];
  const float M3 = ws[L1MF + (4 * r3 + 3) * 8192 + b];

  half2v ii[1][8], pk[1][4];
  half2v cAii[1][8], cBpk[1][4];
  half2v dmy_ii[1][8], dmy_pk[1][4];

  mk_ii(p0, ii[0]);
  pk[0][0] = u2h(p1.x); pk[0][1] = u2h(p1.y); pk[0][2] = u2h(p1.z); pk[0][3] = u2h(p1.w);
  float MA[1] = {M0 + M1};
  combine_d2<1, true>(wsh4, ii, pk, cAii, dmy_pk, MA);

  mk_ii(p2, ii[0]);
  pk[0][0] = u2h(p3.x); pk[0][1] = u2h(p3.y); pk[0][2] = u2h(p3.z); pk[0][3] = u2h(p3.w);
  float MB[1] = {M2 + M3};
  combine_d2<1, false>(wsh4 + 64, ii, pk, dmy_ii, cBpk, MB);

  float M[1] = {MA[0] + MB[0]};
  half2v n[1][4];
  combine_d2<1, false>(wsh4 + 128, cAii, cBpk, dmy_ii, n, M);

  reinterpret_cast<uint4*>(ws + L3NF)[r3 * 8192 + b] =
      uint4{h2u(n[0][0]), h2u(n[0][1]), h2u(n[0][2]), h2u(n[0][3])};
  ws[L3MF + r3 * 8192 + b] = M[0];
}

// ===================== K3: self-prep + layers 4..7 + root, k-parallel =====================
__device__ __forceinline__ float macTd(const uint4* __restrict__ Wr, int myk,
                                       const float* na, const half2v* nbpk) {
  float s = 0.f;
  #pragma unroll
  for (int i = 0; i < 8; ++i) {
    const uint4 w = Wr[myk * 8 + ((i ^ myk) & 7)];
    float T = dd(nbpk[0], u2h(w.x), 0.f);
    T = dd(nbpk[1], u2h(w.y), T);
    T = dd(nbpk[2], u2h(w.z), T);
    T = dd(nbpk[3], u2h(w.w), T);
    s = fmaf(na[i], T, s);
  }
  return s;
}

__global__ __launch_bounds__(NTH) void spn_c(
    const float* __restrict__ w4, const float* __restrict__ w5,
    const float* __restrict__ w6, const float* __restrict__ w7,
    const float* __restrict__ root_w,
    float* __restrict__ ws,
    float* __restrict__ out)
{
  __shared__ float stage[7680];   // 15 regions x 512 f32 = 30 KB
  __shared__ uint4 wsh4[960];     // 15 regions x 64 uint4 = 15 KB (transposed+swizzled)
  __shared__ float ssh[8];
  const int tid = threadIdx.x;

  #pragma unroll
  for (int i = 0; i < 30; ++i) {
    const int idx = tid + 256 * i;
    const int reg = idx >> 9, off = idx & 511;
    const float* src;
    if (reg < 8)       src = w4 + reg * 512;
    else if (reg < 12) src = w5 + (reg - 8) * 512;
    else if (reg < 14) src = w6 + (reg - 12) * 512;
    else               src = w7;
    stage[idx] = src[off];
  }
  if (tid == 255) {
    float m = -3.0e38f;
    for (int k = 0; k < 8; ++k) m = fmaxf(m, root_w[k]);
    float e[8]; float t = 0.f;
    for (int k = 0; k < 8; ++k) { e[k] = __expf(root_w[k] - m); t += e[k]; }
    const float inv = 1.0f / t;
    for (int k = 0; k < 8; ++k) ssh[k] = e[k] * inv;
  }
  __syncthreads();

  if (tid < 120) {
    // transposed [k][i][jp] packed with XOR-swizzled i-chunks
    const int reg = tid >> 3, k = tid & 7;
    float v[64];
    float m = -3.0e38f;
    #pragma unroll
    for (int c = 0; c < 64; ++c) { v[c] = stage[reg * 512 + c * 8 + k]; m = fmaxf(m, v[c]); }
    float t = 0.f;
    #pragma unroll
    for (int c = 0; c < 64; ++c) { v[c] = __expf(v[c] - m); t += v[c]; }
    const float inv = 1.0f / t;
    unsigned* wdwL = reinterpret_cast<unsigned*>(wsh4);
    #pragma unroll
    for (int i = 0; i < 8; ++i)
      #pragma unroll
      for (int jp = 0; jp < 4; ++jp)
        wdwL[reg * 256 + k * 32 + (((i ^ k) & 7) << 2) + jp] =
            h2u(pkrtz(v[i * 8 + 2 * jp] * inv, v[i * 8 + 2 * jp + 1] * inv));
  }
  __syncthreads();

  const int lane = tid & 63, wid = tid >> 6;
  const int myk = lane & 7, bsub = lane >> 3, gbase = lane & 56;
  const int b = blockIdx.x * 32 + wid * 8 + bsub;

  const uint4* n4 = reinterpret_cast<const uint4*>(ws + L3NF);

  // ---- layer 4: 8 regions
  float n4v[8], M4[8];
  #pragma unroll
  for (int r = 0; r < 8; ++r) {
    const uint4 pa = n4[(2 * r + 0) * 8192 + b];
    const uint4 pb = n4[(2 * r + 1) * 8192 + b];
    const float Ma = ws[L3MF + (2 * r + 0) * 8192 + b];
    const float Mb = ws[L3MF + (2 * r + 1) * 8192 + b];
    float na[8];
    const half2v a0 = u2h(pa.x), a1 = u2h(pa.y), a2 = u2h(pa.z), a3 = u2h(pa.w);
    na[0] = (float)a0[0]; na[1] = (float)a0[1];
    na[2] = (float)a1[0]; na[3] = (float)a1[1];
    na[4] = (float)a2[0]; na[5] = (float)a2[1];
    na[6] = (float)a3[0]; na[7] = (float)a3[1];
    half2v nbpk[4] = {u2h(pb.x), u2h(pb.y), u2h(pb.z), u2h(pb.w)};
    float s = macTd(wsh4 + r * 64, myk, na, nbpk);
    float m = s;
    m = fmaxf(m, __shfl_xor(m, 1)); m = fmaxf(m, __shfl_xor(m, 2)); m = fmaxf(m, __shfl_xor(m, 4));
    n4v[r] = s / m;
    M4[r] = Ma + Mb + __logf(m);
  }

  // ---- layer 5: 4 regions
  float n5v[4], M5[4];
  #pragma unroll
  for (int r = 0; r < 4; ++r) {
    float na[8]; half2v nbpk[4];
    #pragma unroll
    for (int i = 0; i < 8; ++i) na[i] = __shfl(n4v[2 * r], gbase + i, 64);
    #pragma unroll
    for (int p = 0; p < 4; ++p)
      nbpk[p] = pkrtz(__shfl(n4v[2 * r + 1], gbase + 2 * p, 64),
                      __shfl(n4v[2 * r + 1], gbase + 2 * p + 1, 64));
    float s = macTd(wsh4 + (8 + r) * 64, myk, na, nbpk);
    float m = s;
    m = fmaxf(m, __shfl_xor(m, 1)); m = fmaxf(m, __shfl_xor(m, 2)); m = fmaxf(m, __shfl_xor(m, 4));
    n5v[r] = s / m;
    M5[r] = M4[2 * r] + M4[2 * r + 1] + __logf(m);
  }

  // ---- layer 6: 2 regions
  float n6v[2], M6[2];
  #pragma unroll
  for (int r = 0; r < 2; ++r) {
    float na[8]; half2v nbpk[4];
    #pragma unroll
    for (int i = 0; i < 8; ++i) na[i] = __shfl(n5v[2 * r], gbase + i, 64);
    #pragma unroll
    for (int p = 0; p < 4; ++p)
      nbpk[p] = pkrtz(__shfl(n5v[2 * r + 1], gbase + 2 * p, 64),
                      __shfl(n5v[2 * r + 1], gbase + 2 * p + 1, 64));
    float s = macTd(wsh4 + (12 + r) * 64, myk, na, nbpk);
    float m = s;
    m = fmaxf(m, __shfl_xor(m, 1)); m = fmaxf(m, __shfl_xor(m, 2)); m = fmaxf(m, __shfl_xor(m, 4));
    n6v[r] = s / m;
    M6[r] = M5[2 * r] + M5[2 * r + 1] + __logf(m);
  }

  // ---- layer 7 + root
  {
    float na[8]; half2v nbpk[4];
    #pragma unroll
    for (int i = 0; i < 8; ++i) na[i] = __shfl(n6v[0], gbase + i, 64);
    #pragma unroll
    for (int p = 0; p < 4; ++p)
      nbpk[p] = pkrtz(__shfl(n6v[1], gbase + 2 * p, 64),
                      __shfl(n6v[1], gbase + 2 * p + 1, 64));
    float s = macTd(wsh4 + 14 * 64, myk, na, nbpk);
    float m = s;
    m = fmaxf(m, __shfl_xor(m, 1)); m = fmaxf(m, __shfl_xor(m, 2)); m = fmaxf(m, __shfl_xor(m, 4));
    const float n7 = s / m;
    const float M7 = M6[0] + M6[1] + __logf(m);
    float prod = n7 * ssh[myk];
    prod += __shfl_xor(prod, 1); prod += __shfl_xor(prod, 2); prod += __shfl_xor(prod, 4);
    if (myk == 0) out[b] = M7 + __logf(prod);
  }
}

// ===================== fallback path (R1 kernel, proven 145us) =====================
static constexpr int NW   = 130560;
static constexpr int AOFF = NW;
static constexpr int BOFF = NW + 2048;
static constexpr int ROFF = NW + 4096;

__device__ __forceinline__ void leaf_eval(float xv, const float* mu8, const float* A8,
                                          const float* B8, float* n, float* M) {
  float h[8];
  float m = -3.0e38f;
  #pragma unroll
  for (int k = 0; k < 8; ++k) {
    const float z = (xv - mu8[k]) * A8[k];
    h[k] = fmaf(-0.5f * z, z, B8[k]);
    m = fmaxf(m, h[k]);
  }
  #pragma unroll
  for (int k = 0; k < 8; ++k) n[k] = __expf(h[k] - m);
  *M = m;
}

__global__ __launch_bounds__(256) void spn_prep(
    const float* __restrict__ ls,
    const float* __restrict__ w0, const float* __restrict__ w1,
    const float* __restrict__ w2, const float* __restrict__ w3,
    const float* __restrict__ w4, const float* __restrict__ w5,
    const float* __restrict__ w6, const float* __restrict__ w7,
    const float* __restrict__ root_w,
    float* __restrict__ ws)
{
  const int job = blockIdx.x * blockDim.x + threadIdx.x;
  if (job < 2040) {
    const float* wl[8] = {w0, w1, w2, w3, w4, w5, w6, w7};
    int j = job, l = 0, base = 0, R = 128;
    while (j >= R * 8) { j -= R * 8; base += R * 512; R >>= 1; ++l; }
    const int r = j >> 3, k = j & 7;
    const float* src = wl[l] + r * 512 + k;
    float v[64];
    float m = -3.0e38f;
    #pragma unroll
    for (int c = 0; c < 64; ++c) { v[c] = src[c * 8]; m = fmaxf(m, v[c]); }
    float ssum = 0.f;
    #pragma unroll
    for (int c = 0; c < 64; ++c) { v[c] = __expf(v[c] - m); ssum += v[c]; }
    const float inv = 1.0f / ssum;
    float* dst = ws + base + r * 512 + k;
    #pragma unroll
    for (int c = 0; c < 64; ++c) dst[c * 8] = v[c] * inv;
  } else if (job < 2040 + 2048) {
    const int i = job - 2040;
    const float l = ls[i];
    ws[AOFF + i] = __expf(-l);
    ws[BOFF + i] = -l - HLP;
  } else if (job == 2040 + 2048) {
    float m = -3.0e38f;
    for (int k = 0; k < 8; ++k) m = fmaxf(m, root_w[k]);
    float e[8]; float ssum = 0.f;
    for (int k = 0; k < 8; ++k) { e[k] = __expf(root_w[k] - m); ssum += e[k]; }
    const float inv = 1.0f / ssum;
    for (int k = 0; k < 8; ++k) ws[ROFF + k] = e[k] * inv;
  }
}

__device__ __forceinline__ void mac64(const float* __restrict__ Wr,
                                      const float* na, const float* nb,
                                      float* s) {
  #pragma unroll
  for (int k = 0; k < 8; ++k) s[k] = 0.f;
  #pragma unroll
  for (int i = 0; i < 8; ++i) {
    const float ai = na[i];
    #pragma unroll
    for (int j = 0; j < 8; ++j) {
      const float e = ai * nb[j];
      const float4 wA = *reinterpret_cast<const float4*>(Wr + (i * 8 + j) * 8);
      const float4 wB = *reinterpret_cast<const float4*>(Wr + (i * 8 + j) * 8 + 4);
      s[0] = fmaf(e, wA.x, s[0]); s[1] = fmaf(e, wA.y, s[1]);
      s[2] = fmaf(e, wA.z, s[2]); s[3] = fmaf(e, wA.w, s[3]);
      s[4] = fmaf(e, wB.x, s[4]); s[5] = fmaf(e, wB.y, s[5]);
      s[6] = fmaf(e, wB.z, s[6]); s[7] = fmaf(e, wB.w, s[7]);
    }
  }
}

#define TB 8
static constexpr int PLA = 128 * 9 + 5;
static constexpr int PLB = 64 * 9 + 5;
static constexpr int NAO = 0;
static constexpr int NBO = TB * PLA;
static constexpr int MAO = NBO + TB * PLB;
static constexpr int MBO = MAO + TB * 128;
static constexpr int SMEM_F = MBO + TB * 64;

__global__ __launch_bounds__(NTH, 2) void spn_main_fb(
    const float* __restrict__ x,
    const float* __restrict__ mu,
    const float* __restrict__ ws,
    float* __restrict__ out)
{
  const float* leafA = ws + AOFF;
  const float* leafB = ws + BOFF;
  const float* srw   = ws + ROFF;

  __shared__ float smem[SMEM_F];

  const int tid = threadIdx.x;
  const int bB = blockIdx.x * TB;

  {
    const float* W0 = ws;
    for (int it = tid; it < TB * 128; it += NTH) {
      const int bb = it & (TB - 1), r = it >> 3;
      float na[8], nb[8], Ma, Mb;
      const int f0 = 2 * r;
      const float xv0 = x[(bB + bb) * 256 + f0];
      const float xv1 = x[(bB + bb) * 256 + f0 + 1];
      leaf_eval(xv0, mu + f0 * 8, leafA + f0 * 8, leafB + f0 * 8, na, &Ma);
      leaf_eval(xv1, mu + f0 * 8 + 8, leafA + f0 * 8 + 8, leafB + f0 * 8 + 8, nb, &Mb);
      float s[8];
      mac64(W0 + r * 512, na, nb, s);
      const float smax = max8(s);
      const float inv = 1.0f / smax;
      const int ob = NAO + bb * PLA + r * 9;
      #pragma unroll
      for (int k = 0; k < 8; ++k) smem[ob + k] = s[k] * inv;
      smem[MAO + bb * 128 + r] = Ma + Mb + __logf(smax);
    }
  }
  __syncthreads();

  int pinO = NAO, poutO = NBO;
  int MinO = MAO, MoutO = MBO;
  int PLIN = PLA, PLOUT = PLB;
  int Rin = 128;
  const float* Wl = ws + 128 * 512;
  for (int l = 1; l < 7; ++l) {
    const int Rout = Rin >> 1;
    for (int it = tid; it < TB * Rout; it += NTH) {
      const int bb = it & (TB - 1), r = it >> 3;
      float na[8], nb[8];
      const int ia = pinO + bb * PLIN + (2 * r) * 9;
      #pragma unroll
      for (int i = 0; i < 8; ++i) { na[i] = smem[ia + i]; nb[i] = smem[ia + 9 + i]; }
      float s[8];
      mac64(Wl + r * 512, na, nb, s);
      const float smax = max8(s);
      const float inv = 1.0f / smax;
      const int ob = poutO + bb * PLOUT + r * 9;
      #pragma unroll
      for (int k = 0; k < 8; ++k) smem[ob + k] = s[k] * inv;
      smem[MoutO + bb * Rout + r] =
          smem[MinO + bb * Rin + 2 * r] + smem[MinO + bb * Rin + 2 * r + 1] + __logf(smax);
    }
    __syncthreads();
    int t;
    t = pinO; pinO = poutO; poutO = t;
    t = MinO; MinO = MoutO; MoutO = t;
    t = PLIN; PLIN = PLOUT; PLOUT = t;
    Rin = Rout;
    Wl += Rout * 512;
  }

  for (int it = tid; it < TB; it += NTH) {
    const int bb = it;
    float na[8], nb[8];
    const int ia = pinO + bb * PLIN;
    #pragma unroll
    for (int i = 0; i < 8; ++i) { na[i] = smem[ia + i]; nb[i] = smem[ia + 9 + i]; }
    float s[8];
    mac64(Wl, na, nb, s);
    float acc = 0.f;
    #pragma unroll
    for (int k = 0; k < 8; ++k) acc = fmaf(s[k], srw[k], acc);
    out[bB + bb] = smem[MinO + bb * 2] + smem[MinO + bb * 2 + 1] + __logf(acc);
  }
}

extern "C" void kernel_launch(void* const* d_in, const int* in_sizes, int n_in,
                              void* d_out, int out_size, void* d_ws, size_t ws_size,
                              hipStream_t stream) {
  (void)in_sizes; (void)n_in; (void)out_size;
  const float* x      = (const float*)d_in[0];
  const float* mu     = (const float*)d_in[1];
  const float* ls     = (const float*)d_in[2];
  const float* w0     = (const float*)d_in[3];
  const float* w1     = (const float*)d_in[4];
  const float* w2     = (const float*)d_in[5];
  const float* w3     = (const float*)d_in[6];
  const float* w4     = (const float*)d_in[7];
  const float* w5     = (const float*)d_in[8];
  const float* w6     = (const float*)d_in[9];
  const float* w7     = (const float*)d_in[10];
  const float* root_w = (const float*)d_in[11];
  float* ws  = (float*)d_ws;
  float* out = (float*)d_out;

  if (ws_size >= WS_NEED_B) {
    spn_a<<<1024, NTH, 0, stream>>>(x, mu, ls, w0, w1, ws);
    spn_b<<<512, NTH, 0, stream>>>(w2, w3, ws);
    spn_c<<<256, NTH, 0, stream>>>(w4, w5, w6, w7, root_w, ws, out);
  } else {
    spn_prep<<<16, 256, 0, stream>>>(ls, w0, w1, w2, w3, w4, w5, w6, w7, root_w, ws);
    spn_main_fb<<<8192 / TB, NTH, 0, stream>>>(x, mu, ws, out);
  }
}

// Round 9
// 50.680 us; speedup vs baseline: 1.1722x; 1.0211x over previous
//
#include <hip/hip_runtime.h>
#include <math.h>

#define NTH 256

static constexpr float HLP = 0.9189385332046727f; // 0.5*log(2*pi)

typedef __attribute__((ext_vector_type(2))) _Float16 half2v;
typedef __attribute__((ext_vector_type(2))) __fp16   fp16x2;

// ===================== main-path ws layout =====================
// [0, 524288)        L3 n f16-packed uint4 [16][8192]  (uint4 idx r3*8192+b)
// [524288, 655360)   L3 M f32 [16][8192]
static constexpr int L3MF = 524288;
static constexpr size_t WS_NEED_B = (size_t)655360 * 4;   // 2.62 MB

// ===================== helpers =====================
__device__ __forceinline__ half2v pkrtz(float a, float b) {
  return __builtin_bit_cast(half2v, __builtin_amdgcn_cvt_pkrtz(a, b));
}
__device__ __forceinline__ half2v u2h(unsigned u) {
  return __builtin_bit_cast(half2v, u);
}
__device__ __forceinline__ unsigned h2u(half2v h) {
  return __builtin_bit_cast(unsigned, h);
}
__device__ __forceinline__ float dd(half2v a, half2v b, float c) {
#if __has_builtin(__builtin_amdgcn_fdot2)
  return __builtin_amdgcn_fdot2(__builtin_bit_cast(fp16x2, a),
                                __builtin_bit_cast(fp16x2, b), c, false);
#else
  return fmaf((float)a[0], (float)b[0], fmaf((float)a[1], (float)b[1], c));
#endif
}
__device__ __forceinline__ float max8(const float* s) {
  float m = s[0];
  #pragma unroll
  for (int k = 1; k < 8; ++k) m = fmaxf(m, s[k]);
  return m;
}

__device__ __forceinline__ void leaf_ii(float xv, const float* mu8, const float* A8,
                                        const float* B8, half2v* ii, float* M) {
  float h[8];
  float m = -3.0e38f;
  #pragma unroll
  for (int k = 0; k < 8; ++k) {
    const float z = (xv - mu8[k]) * A8[k];
    h[k] = fmaf(-0.5f * z, z, B8[k]);
    m = fmaxf(m, h[k]);
  }
  #pragma unroll
  for (int k = 0; k < 8; ++k) {
    const float n = __expf(h[k] - m);
    ii[k] = pkrtz(n, n);
  }
  *M = m;
}
__device__ __forceinline__ void leaf_pk(float xv, const float* mu8, const float* A8,
                                        const float* B8, half2v* pk, float* M) {
  float h[8];
  float m = -3.0e38f;
  #pragma unroll
  for (int k = 0; k < 8; ++k) {
    const float z = (xv - mu8[k]) * A8[k];
    h[k] = fmaf(-0.5f * z, z, B8[k]);
    m = fmaxf(m, h[k]);
  }
  #pragma unroll
  for (int p = 0; p < 4; ++p) {
    const float n0 = __expf(h[2 * p] - m);
    const float n1 = __expf(h[2 * p + 1] - m);
    pk[p] = pkrtz(n0, n1);
  }
  *M = m;
}

// combine via dot2: s[k] = sum_{i,j} na_i nb_j W[i*8+j][k]
template<int G, bool OUT_II>
__device__ __forceinline__ void combine_d2(const uint4* __restrict__ WL,
                                           const half2v (&na)[G][8],
                                           const half2v (&nb)[G][4],
                                           half2v (&oii)[G][8],
                                           half2v (&opk)[G][4],
                                           float (&M)[G]) {
  float s[G][8];
  #pragma unroll
  for (int g = 0; g < G; ++g)
    #pragma unroll
    for (int k = 0; k < 8; ++k) s[g][k] = 0.f;

  #pragma unroll
  for (int i = 0; i < 8; ++i) {
    half2v e[G][4];
    #pragma unroll
    for (int g = 0; g < G; ++g) {
      e[g][0] = na[g][i] * nb[g][0];
      e[g][1] = na[g][i] * nb[g][1];
      e[g][2] = na[g][i] * nb[g][2];
      e[g][3] = na[g][i] * nb[g][3];
    }
    #pragma unroll
    for (int k = 0; k < 8; ++k) {
      const uint4 w = WL[i * 8 + k];
      #pragma unroll
      for (int g = 0; g < G; ++g) {
        float acc = s[g][k];
        acc = dd(e[g][0], u2h(w.x), acc);
        acc = dd(e[g][1], u2h(w.y), acc);
        acc = dd(e[g][2], u2h(w.z), acc);
        acc = dd(e[g][3], u2h(w.w), acc);
        s[g][k] = acc;
      }
    }
  }
  #pragma unroll
  for (int g = 0; g < G; ++g) {
    const float smax = max8(s[g]);
    const float inv = 1.0f / smax;
    if constexpr (OUT_II) {
      #pragma unroll
      for (int p = 0; p < 8; ++p) {
        const float n = s[g][p] * inv;
        oii[g][p] = pkrtz(n, n);
      }
    } else {
      #pragma unroll
      for (int p = 0; p < 4; ++p)
        opk[g][p] = pkrtz(s[g][2 * p] * inv, s[g][2 * p + 1] * inv);
    }
    M[g] += __logf(smax);
  }
}

// block-local softmax of one column (r,k) from stage into packed [c][k]-pair layout
__device__ __forceinline__ void prep_col_std(const float* stage, unsigned* wdwL,
                                             int r, int k) {
  float v[64];
  float m = -3.0e38f;
  #pragma unroll
  for (int c = 0; c < 64; ++c) { v[c] = stage[r * 512 + c * 8 + k]; m = fmaxf(m, v[c]); }
  float t = 0.f;
  #pragma unroll
  for (int c = 0; c < 64; ++c) { v[c] = __expf(v[c] - m); t += v[c]; }
  const float inv = 1.0f / t;
  #pragma unroll
  for (int i = 0; i < 8; ++i)
    #pragma unroll
    for (int jp = 0; jp < 4; ++jp)
      wdwL[r * 256 + (i * 8 + k) * 4 + jp] =
          h2u(pkrtz(v[i * 8 + 2 * jp] * inv, v[i * 8 + 2 * jp + 1] * inv));
}

// one L0-pair + L0-pair + L1 subtree; xv = 4 features' x values.
// lsh: [0..127] mu, [128..255] A, [256..383] B for the block's 16 features.
template<bool OUT_II>
__device__ __forceinline__ void subtree_eval(const uint4* __restrict__ wsh4, int sub,
                                             const float* lsh, float4 xv,
                                             half2v (&oii)[1][8], half2v (&opk)[1][4],
                                             float* Mout) {
  half2v ii[1][8], pk[1][4];
  half2v aii[1][8], bpk[1][4];
  half2v dii[1][8], dpk[1][4];
  float Ma, Mb;
  const int fl = 4 * sub;

  leaf_ii(xv.x, lsh + fl * 8,       lsh + 128 + fl * 8,       lsh + 256 + fl * 8,       ii[0], &Ma);
  leaf_pk(xv.y, lsh + (fl + 1) * 8, lsh + 128 + (fl + 1) * 8, lsh + 256 + (fl + 1) * 8, pk[0], &Mb);
  float MA[1] = {Ma + Mb};
  combine_d2<1, true>(wsh4 + (2 * sub) * 64, ii, pk, aii, dpk, MA);

  leaf_ii(xv.z, lsh + (fl + 2) * 8, lsh + 128 + (fl + 2) * 8, lsh + 256 + (fl + 2) * 8, ii[0], &Ma);
  leaf_pk(xv.w, lsh + (fl + 3) * 8, lsh + 128 + (fl + 3) * 8, lsh + 256 + (fl + 3) * 8, pk[0], &Mb);
  float MB[1] = {Ma + Mb};
  combine_d2<1, false>(wsh4 + (2 * sub + 1) * 64, ii, pk, dii, bpk, MB);

  float M[1] = {MA[0] + MB[0]};
  combine_d2<1, OUT_II>(wsh4 + (8 + sub) * 64, aii, bpk, oii, opk, M);
  *Mout = M[0];
}

// ===================== K1: fused L0..L3 per (r3, 256-batch chunk) =====================
// grid: 16 r3 x 32 chunks = 512 blocks x 256 thr; thread = 1 batch, 15 combines
__global__ __launch_bounds__(NTH, 2) void spn_ab(
    const float* __restrict__ x,
    const float* __restrict__ mu,
    const float* __restrict__ ls,
    const float* __restrict__ w0, const float* __restrict__ w1,
    const float* __restrict__ w2, const float* __restrict__ w3,
    float* __restrict__ ws)
{
  __shared__ float stage[7680];   // 15 regions x 512 f32 = 30 KB
  __shared__ uint4 wsh4[960];     // 15 regions x 64 uint4 = 15 KB packed f16
  __shared__ float lsh[384];      // mu/A/B for 16 features x 8
  const int tid = threadIdx.x;
  const int r3 = blockIdx.x >> 5;
  const int chunk = blockIdx.x & 31;

  // stage raw weights for this block's 15 regions (coalesced)
  #pragma unroll
  for (int i = 0; i < 30; ++i) {
    const int idx = tid + 256 * i;
    const int reg = idx >> 9, off = idx & 511;
    const float* src;
    if (reg < 8)       src = w0 + (8 * r3 + reg) * 512;
    else if (reg < 12) src = w1 + (4 * r3 + (reg - 8)) * 512;
    else if (reg < 14) src = w2 + (2 * r3 + (reg - 12)) * 512;
    else               src = w3 + r3 * 512;
    stage[idx] = src[off];
  }
  if (tid < 128) {
    const int base = r3 * 128;   // 16 features x 8
    const float l = ls[base + tid];
    lsh[tid]       = mu[base + tid];
    lsh[128 + tid] = __expf(-l);
    lsh[256 + tid] = -l - HLP;
  }
  __syncthreads();

  if (tid < 120) prep_col_std(stage, reinterpret_cast<unsigned*>(wsh4), tid >> 3, tid & 7);
  __syncthreads();

  const int b = chunk * 256 + tid;
  const float* xb = x + (size_t)b * 256 + 16 * r3;
  const float4 xv0 = *reinterpret_cast<const float4*>(xb);
  const float4 xv1 = *reinterpret_cast<const float4*>(xb + 4);
  const float4 xv2 = *reinterpret_cast<const float4*>(xb + 8);
  const float4 xv3 = *reinterpret_cast<const float4*>(xb + 12);

  half2v s0ii[1][8], s1pk[1][4], s2ii[1][8], s3pk[1][4];
  half2v dii[1][8], dpk[1][4];
  float M0, M1, M2, M3;

  subtree_eval<true >(wsh4, 0, lsh, xv0, s0ii, dpk, &M0);
  subtree_eval<false>(wsh4, 1, lsh, xv1, dii, s1pk, &M1);
  float MA[1] = {M0 + M1};
  half2v cAii[1][8];
  combine_d2<1, true>(wsh4 + 12 * 64, s0ii, s1pk, cAii, dpk, MA);

  subtree_eval<true >(wsh4, 2, lsh, xv2, s2ii, dpk, &M2);
  subtree_eval<false>(wsh4, 3, lsh, xv3, dii, s3pk, &M3);
  float MB[1] = {M2 + M3};
  half2v cBpk[1][4];
  combine_d2<1, false>(wsh4 + 13 * 64, s2ii, s3pk, dii, cBpk, MB);

  float M[1] = {MA[0] + MB[0]};
  half2v n[1][4];
  combine_d2<1, false>(wsh4 + 14 * 64, cAii, cBpk, dii, n, M);

  reinterpret_cast<uint4*>(ws)[r3 * 8192 + b] =
      uint4{h2u(n[0][0]), h2u(n[0][1]), h2u(n[0][2]), h2u(n[0][3])};
  ws[L3MF + r3 * 8192 + b] = M[0];
}

// ===================== K2: self-prep + layers 4..7 + root, k-parallel =====================
__device__ __forceinline__ float macTd(const uint4* __restrict__ Wr, int myk,
                                       const float* na, const half2v* nbpk) {
  float s = 0.f;
  #pragma unroll
  for (int i = 0; i < 8; ++i) {
    const uint4 w = Wr[myk * 8 + ((i ^ myk) & 7)];
    float T = dd(nbpk[0], u2h(w.x), 0.f);
    T = dd(nbpk[1], u2h(w.y), T);
    T = dd(nbpk[2], u2h(w.z), T);
    T = dd(nbpk[3], u2h(w.w), T);
    s = fmaf(na[i], T, s);
  }
  return s;
}

__global__ __launch_bounds__(NTH) void spn_c(
    const float* __restrict__ w4, const float* __restrict__ w5,
    const float* __restrict__ w6, const float* __restrict__ w7,
    const float* __restrict__ root_w,
    float* __restrict__ ws,
    float* __restrict__ out)
{
  __shared__ float stage[7680];   // 15 regions x 512 f32 = 30 KB
  __shared__ uint4 wsh4[960];     // 15 regions x 64 uint4 = 15 KB (transposed+swizzled)
  __shared__ float ssh[8];
  const int tid = threadIdx.x;

  #pragma unroll
  for (int i = 0; i < 30; ++i) {
    const int idx = tid + 256 * i;
    const int reg = idx >> 9, off = idx & 511;
    const float* src;
    if (reg < 8)       src = w4 + reg * 512;
    else if (reg < 12) src = w5 + (reg - 8) * 512;
    else if (reg < 14) src = w6 + (reg - 12) * 512;
    else               src = w7;
    stage[idx] = src[off];
  }
  if (tid == 255) {
    float m = -3.0e38f;
    for (int k = 0; k < 8; ++k) m = fmaxf(m, root_w[k]);
    float e[8]; float t = 0.f;
    for (int k = 0; k < 8; ++k) { e[k] = __expf(root_w[k] - m); t += e[k]; }
    const float inv = 1.0f / t;
    for (int k = 0; k < 8; ++k) ssh[k] = e[k] * inv;
  }
  __syncthreads();

  if (tid < 120) {
    // transposed [k][i][jp] packed with XOR-swizzled i-chunks
    const int reg = tid >> 3, k = tid & 7;
    float v[64];
    float m = -3.0e38f;
    #pragma unroll
    for (int c = 0; c < 64; ++c) { v[c] = stage[reg * 512 + c * 8 + k]; m = fmaxf(m, v[c]); }
    float t = 0.f;
    #pragma unroll
    for (int c = 0; c < 64; ++c) { v[c] = __expf(v[c] - m); t += v[c]; }
    const float inv = 1.0f / t;
    unsigned* wdwL = reinterpret_cast<unsigned*>(wsh4);
    #pragma unroll
    for (int i = 0; i < 8; ++i)
      #pragma unroll
      for (int jp = 0; jp < 4; ++jp)
        wdwL[reg * 256 + k * 32 + (((i ^ k) & 7) << 2) + jp] =
            h2u(pkrtz(v[i * 8 + 2 * jp] * inv, v[i * 8 + 2 * jp + 1] * inv));
  }
  __syncthreads();

  const int lane = tid & 63, wid = tid >> 6;
  const int myk = lane & 7, bsub = lane >> 3, gbase = lane & 56;
  const int b = blockIdx.x * 32 + wid * 8 + bsub;

  const uint4* n4 = reinterpret_cast<const uint4*>(ws);

  // ---- layer 4: 8 regions
  float n4v[8], M4[8];
  #pragma unroll
  for (int r = 0; r < 8; ++r) {
    const uint4 pa = n4[(2 * r + 0) * 8192 + b];
    const uint4 pb = n4[(2 * r + 1) * 8192 + b];
    const float Ma = ws[L3MF + (2 * r + 0) * 8192 + b];
    const float Mb = ws[L3MF + (2 * r + 1) * 8192 + b];
    float na[8];
    const half2v a0 = u2h(pa.x), a1 = u2h(pa.y), a2 = u2h(pa.z), a3 = u2h(pa.w);
    na[0] = (float)a0[0]; na[1] = (float)a0[1];
    na[2] = (float)a1[0]; na[3] = (float)a1[1];
    na[4] = (float)a2[0]; na[5] = (float)a2[1];
    na[6] = (float)a3[0]; na[7] = (float)a3[1];
    half2v nbpk[4] = {u2h(pb.x), u2h(pb.y), u2h(pb.z), u2h(pb.w)};
    float s = macTd(wsh4 + r * 64, myk, na, nbpk);
    float m = s;
    m = fmaxf(m, __shfl_xor(m, 1)); m = fmaxf(m, __shfl_xor(m, 2)); m = fmaxf(m, __shfl_xor(m, 4));
    n4v[r] = s / m;
    M4[r] = Ma + Mb + __logf(m);
  }

  // ---- layer 5: 4 regions
  float n5v[4], M5[4];
  #pragma unroll
  for (int r = 0; r < 4; ++r) {
    float na[8]; half2v nbpk[4];
    #pragma unroll
    for (int i = 0; i < 8; ++i) na[i] = __shfl(n4v[2 * r], gbase + i, 64);
    #pragma unroll
    for (int p = 0; p < 4; ++p)
      nbpk[p] = pkrtz(__shfl(n4v[2 * r + 1], gbase + 2 * p, 64),
                      __shfl(n4v[2 * r + 1], gbase + 2 * p + 1, 64));
    float s = macTd(wsh4 + (8 + r) * 64, myk, na, nbpk);
    float m = s;
    m = fmaxf(m, __shfl_xor(m, 1)); m = fmaxf(m, __shfl_xor(m, 2)); m = fmaxf(m, __shfl_xor(m, 4));
    n5v[r] = s / m;
    M5[r] = M4[2 * r] + M4[2 * r + 1] + __logf(m);
  }

  // ---- layer 6: 2 regions
  float n6v[2], M6[2];
  #pragma unroll
  for (int r = 0; r < 2; ++r) {
    float na[8]; half2v nbpk[4];
    #pragma unroll
    for (int i = 0; i < 8; ++i) na[i] = __shfl(n5v[2 * r], gbase + i, 64);
    #pragma unroll
    for (int p = 0; p < 4; ++p)
      nbpk[p] = pkrtz(__shfl(n5v[2 * r + 1], gbase + 2 * p, 64),
                      __shfl(n5v[2 * r + 1], gbase + 2 * p + 1, 64));
    float s = macTd(wsh4 + (12 + r) * 64, myk, na, nbpk);
    float m = s;
    m = fmaxf(m, __shfl_xor(m, 1)); m = fmaxf(m, __shfl_xor(m, 2)); m = fmaxf(m, __shfl_xor(m, 4));
    n6v[r] = s / m;
    M6[r] = M5[2 * r] + M5[2 * r + 1] + __logf(m);
  }

  // ---- layer 7 + root
  {
    float na[8]; half2v nbpk[4];
    #pragma unroll
    for (int i = 0; i < 8; ++i) na[i] = __shfl(n6v[0], gbase + i, 64);
    #pragma unroll
    for (int p = 0; p < 4; ++p)
      nbpk[p] = pkrtz(__shfl(n6v[1], gbase + 2 * p, 64),
                      __shfl(n6v[1], gbase + 2 * p + 1, 64));
    float s = macTd(wsh4 + 14 * 64, myk, na, nbpk);
    float m = s;
    m = fmaxf(m, __shfl_xor(m, 1)); m = fmaxf(m, __shfl_xor(m, 2)); m = fmaxf(m, __shfl_xor(m, 4));
    const float n7 = s / m;
    const float M7 = M6[0] + M6[1] + __logf(m);
    float prod = n7 * ssh[myk];
    prod += __shfl_xor(prod, 1); prod += __shfl_xor(prod, 2); prod += __shfl_xor(prod, 4);
    if (myk == 0) out[b] = M7 + __logf(prod);
  }
}

// ===================== fallback path (R1 kernel, proven 145us) =====================
static constexpr int NW   = 130560;
static constexpr int AOFF = NW;
static constexpr int BOFF = NW + 2048;
static constexpr int ROFF = NW + 4096;

__device__ __forceinline__ void leaf_eval(float xv, const float* mu8, const float* A8,
                                          const float* B8, float* n, float* M) {
  float h[8];
  float m = -3.0e38f;
  #pragma unroll
  for (int k = 0; k < 8; ++k) {
    const float z = (xv - mu8[k]) * A8[k];
    h[k] = fmaf(-0.5f * z, z, B8[k]);
    m = fmaxf(m, h[k]);
  }
  #pragma unroll
  for (int k = 0; k < 8; ++k) n[k] = __expf(h[k] - m);
  *M = m;
}

__global__ __launch_bounds__(256) void spn_prep(
    const float* __restrict__ ls,
    const float* __restrict__ w0, const float* __restrict__ w1,
    const float* __restrict__ w2, const float* __restrict__ w3,
    const float* __restrict__ w4, const float* __restrict__ w5,
    const float* __restrict__ w6, const float* __restrict__ w7,
    const float* __restrict__ root_w,
    float* __restrict__ ws)
{
  const int job = blockIdx.x * blockDim.x + threadIdx.x;
  if (job < 2040) {
    const float* wl[8] = {w0, w1, w2, w3, w4, w5, w6, w7};
    int j = job, l = 0, base = 0, R = 128;
    while (j >= R * 8) { j -= R * 8; base += R * 512; R >>= 1; ++l; }
    const int r = j >> 3, k = j & 7;
    const float* src = wl[l] + r * 512 + k;
    float v[64];
    float m = -3.0e38f;
    #pragma unroll
    for (int c = 0; c < 64; ++c) { v[c] = src[c * 8]; m = fmaxf(m, v[c]); }
    float ssum = 0.f;
    #pragma unroll
    for (int c = 0; c < 64; ++c) { v[c] = __expf(v[c] - m); ssum += v[c]; }
    const float inv = 1.0f / ssum;
    float* dst = ws + base + r * 512 + k;
    #pragma unroll
    for (int c = 0; c < 64; ++c) dst[c * 8] = v[c] * inv;
  } else if (job < 2040 + 2048) {
    const int i = job - 2040;
    const float l = ls[i];
    ws[AOFF + i] = __expf(-l);
    ws[BOFF + i] = -l - HLP;
  } else if (job == 2040 + 2048) {
    float m = -3.0e38f;
    for (int k = 0; k < 8; ++k) m = fmaxf(m, root_w[k]);
    float e[8]; float ssum = 0.f;
    for (int k = 0; k < 8; ++k) { e[k] = __expf(root_w[k] - m); ssum += e[k]; }
    const float inv = 1.0f / ssum;
    for (int k = 0; k < 8; ++k) ws[ROFF + k] = e[k] * inv;
  }
}

__device__ __forceinline__ void mac64(const float* __restrict__ Wr,
                                      const float* na, const float* nb,
                                      float* s) {
  #pragma unroll
  for (int k = 0; k < 8; ++k) s[k] = 0.f;
  #pragma unroll
  for (int i = 0; i < 8; ++i) {
    const float ai = na[i];
    #pragma unroll
    for (int j = 0; j < 8; ++j) {
      const float e = ai * nb[j];
      const float4 wA = *reinterpret_cast<const float4*>(Wr + (i * 8 + j) * 8);
      const float4 wB = *reinterpret_cast<const float4*>(Wr + (i * 8 + j) * 8 + 4);
      s[0] = fmaf(e, wA.x, s[0]); s[1] = fmaf(e, wA.y, s[1]);
      s[2] = fmaf(e, wA.z, s[2]); s[3] = fmaf(e, wA.w, s[3]);
      s[4] = fmaf(e, wB.x, s[4]); s[5] = fmaf(e, wB.y, s[5]);
      s[6] = fmaf(e, wB.z, s[6]); s[7] = fmaf(e, wB.w, s[7]);
    }
  }
}

#define TB 8
static constexpr int PLA = 128 * 9 + 5;
static constexpr int PLB = 64 * 9 + 5;
static constexpr int NAO = 0;
static constexpr int NBO = TB * PLA;
static constexpr int MAO = NBO + TB * PLB;
static constexpr int MBO = MAO + TB * 128;
static constexpr int SMEM_F = MBO + TB * 64;

__global__ __launch_bounds__(NTH, 2) void spn_main_fb(
    const float* __restrict__ x,
    const float* __restrict__ mu,
    const float* __restrict__ ws,
    float* __restrict__ out)
{
  const float* leafA = ws + AOFF;
  const float* leafB = ws + BOFF;
  const float* srw   = ws + ROFF;

  __shared__ float smem[SMEM_F];

  const int tid = threadIdx.x;
  const int bB = blockIdx.x * TB;

  {
    const float* W0 = ws;
    for (int it = tid; it < TB * 128; it += NTH) {
      const int bb = it & (TB - 1), r = it >> 3;
      float na[8], nb[8], Ma, Mb;
      const int f0 = 2 * r;
      const float xv0 = x[(bB + bb) * 256 + f0];
      const float xv1 = x[(bB + bb) * 256 + f0 + 1];
      leaf_eval(xv0, mu + f0 * 8, leafA + f0 * 8, leafB + f0 * 8, na, &Ma);
      leaf_eval(xv1, mu + f0 * 8 + 8, leafA + f0 * 8 + 8, leafB + f0 * 8 + 8, nb, &Mb);
      float s[8];
      mac64(W0 + r * 512, na, nb, s);
      const float smax = max8(s);
      const float inv = 1.0f / smax;
      const int ob = NAO + bb * PLA + r * 9;
      #pragma unroll
      for (int k = 0; k < 8; ++k) smem[ob + k] = s[k] * inv;
      smem[MAO + bb * 128 + r] = Ma + Mb + __logf(smax);
    }
  }
  __syncthreads();

  int pinO = NAO, poutO = NBO;
  int MinO = MAO, MoutO = MBO;
  int PLIN = PLA, PLOUT = PLB;
  int Rin = 128;
  const float* Wl = ws + 128 * 512;
  for (int l = 1; l < 7; ++l) {
    const int Rout = Rin >> 1;
    for (int it = tid; it < TB * Rout; it += NTH) {
      const int bb = it & (TB - 1), r = it >> 3;
      float na[8], nb[8];
      const int ia = pinO + bb * PLIN + (2 * r) * 9;
      #pragma unroll
      for (int i = 0; i < 8; ++i) { na[i] = smem[ia + i]; nb[i] = smem[ia + 9 + i]; }
      float s[8];
      mac64(Wl + r * 512, na, nb, s);
      const float smax = max8(s);
      const float inv = 1.0f / smax;
      const int ob = poutO + bb * PLOUT + r * 9;
      #pragma unroll
      for (int k = 0; k < 8; ++k) smem[ob + k] = s[k] * inv;
      smem[MoutO + bb * Rout + r] =
          smem[MinO + bb * Rin + 2 * r] + smem[MinO + bb * Rin + 2 * r + 1] + __logf(smax);
    }
    __syncthreads();
    int t;
    t = pinO; pinO = poutO; poutO = t;
    t = MinO; MinO = MoutO; MoutO = t;
    t = PLIN; PLIN = PLOUT; PLOUT = t;
    Rin = Rout;
    Wl += Rout * 512;
  }

  for (int it = tid; it < TB; it += NTH) {
    const int bb = it;
    float na[8], nb[8];
    const int ia = pinO + bb * PLIN;
    #pragma unroll
    for (int i = 0; i < 8; ++i) { na[i] = smem[ia + i]; nb[i] = smem[ia + 9 + i]; }
    float s[8];
    mac64(Wl, na, nb, s);
    float acc = 0.f;
    #pragma unroll
    for (int k = 0; k < 8; ++k) acc = fmaf(s[k], srw[k], acc);
    out[bB + bb] = smem[MinO + bb * 2] + smem[MinO + bb * 2 + 1] + __logf(acc);
  }
}

extern "C" void kernel_launch(void* const* d_in, const int* in_sizes, int n_in,
                              void* d_out, int out_size, void* d_ws, size_t ws_size,
                              hipStream_t stream) {
  (void)in_sizes; (void)n_in; (void)out_size;
  const float* x      = (const float*)d_in[0];
  const float* mu     = (const float*)d_in[1];
  const float* ls     = (const float*)d_in[2];
  const float* w0     = (const float*)d_in[3];
  const float* w1     = (const float*)d_in[4];
  const float* w2     = (const float*)d_in[5];
  const float* w3     = (const float*)d_in[6];
  const float* w4     = (const float*)d_in[7];
  const float* w5     = (const float*)d_in[8];
  const float* w6     = (const float*)d_in[9];
  const float* w7     = (const float*)d_in[10];
  const float* root_w = (const float*)d_in[11];
  float* ws  = (float*)d_ws;
  float* out = (float*)d_out;

  if (ws_size >= WS_NEED_B) {
    spn_ab<<<512, NTH, 0, stream>>>(x, mu, ls, w0, w1, w2, w3, ws);
    spn_c<<<256, NTH, 0, stream>>>(w4, w5, w6, w7, root_w, ws, out);
  } else {
    spn_prep<<<16, 256, 0, stream>>>(ls, w0, w1, w2, w3, w4, w5, w6, w7, root_w, ws);
    spn_main_fb<<<8192 / TB, NTH, 0, stream>>>(x, mu, ws, out);
  }
}